// Round 2
// baseline (339.143 us; speedup 1.0000x reference)
//
#include <hip/hip_runtime.h>

#define NB 16
#define NH 256
#define NL 4096
#define NN 32

__device__ __forceinline__ unsigned short f2bf(float x) {
    unsigned int u = __float_as_uint(x);
    unsigned int r = u + 0x7FFFu + ((u >> 16) & 1u);
    return (unsigned short)(r >> 16);
}
__device__ __forceinline__ float bf2f(unsigned short b) {
    return __uint_as_float(((unsigned int)b) << 16);
}

// consts layout per h (192 floats): [0..31]=wr [32..63]=wi [64..95]=c2r [96..127]=c2i
// [128..159]=W16r [160..191]=W16i   where w=exp(dt*A), c2=2*C*(exp(dt*A)-1)/A, W16=w^16
__global__ void precompute_kernel(const float* __restrict__ log_dt,
                                  const float* __restrict__ Cr,
                                  const float* __restrict__ Ci,
                                  const float* __restrict__ lar,
                                  const float* __restrict__ aim,
                                  float* __restrict__ consts) {
    int idx = blockIdx.x * blockDim.x + threadIdx.x;  // h*32 + n
    if (idx >= NH * NN) return;
    int h = idx >> 5, n = idx & 31;
    float dt = expf(log_dt[h]);
    float ar = -expf(lar[idx]);
    float ai = aim[idx];
    float dar = ar * dt, dai = ai * dt;
    float er = expf(dar);
    float wr = er * cosf(dai), wi = er * sinf(dai);
    // E = exp(dtA) - 1 ; f = E / A = E*conj(A)/|A|^2
    float Er = wr - 1.0f, Ei = wi;
    float den = ar * ar + ai * ai;
    float fr = (Er * ar + Ei * ai) / den;
    float fi = (Ei * ar - Er * ai) / den;
    float cr = Cr[idx], ci = Ci[idx];
    float c2r = 2.0f * (cr * fr - ci * fi);
    float c2i = 2.0f * (cr * fi + ci * fr);
    // w^16 computed directly: exp(16*dtA) (more accurate than 4 squarings)
    float e16 = expf(16.0f * dar);
    float W16r = e16 * cosf(16.0f * dai);
    float W16i = e16 * sinf(16.0f * dai);
    float* ch = consts + h * 192;
    ch[n]       = wr;  ch[32 + n]  = wi;
    ch[64 + n]  = c2r; ch[96 + n]  = c2i;
    ch[128 + n] = W16r; ch[160 + n] = W16i;
}

// One block per (b,h). 256 threads, each owns 16 contiguous time steps.
// Phase A: chunk-local states. Phase B: carry scan across 256 chunks
// (4-segment split scan on wave 0). Phase C: recompute with carries, accumulate y.
// Epilogue: y += u*D; exact GELU; store bf16.
__global__ __launch_bounds__(256) void scan_kernel(const float* __restrict__ u,
                                                   const float* __restrict__ consts,
                                                   const float* __restrict__ Dvec,
                                                   unsigned short* __restrict__ ybf) {
    const int bh = blockIdx.x;
    const int h = bh & (NH - 1);
    const int tid = threadIdx.x;

    __shared__ float ldsC[192];
    __shared__ float ldsP[16][257][2];  // pad 257: phase-B column access conflict-free

    if (tid < 192) ldsC[tid] = consts[h * 192 + tid];

    const float* urow = u + (size_t)bh * NL;
    float uv[16];
    {
        const float4* up = (const float4*)(urow + tid * 16);
        float4 a = up[0], b4 = up[1], c4 = up[2], d4 = up[3];
        uv[0]=a.x; uv[1]=a.y; uv[2]=a.z; uv[3]=a.w;
        uv[4]=b4.x; uv[5]=b4.y; uv[6]=b4.z; uv[7]=b4.w;
        uv[8]=c4.x; uv[9]=c4.y; uv[10]=c4.z; uv[11]=c4.w;
        uv[12]=d4.x; uv[13]=d4.y; uv[14]=d4.z; uv[15]=d4.w;
    }
    float y[16];
    #pragma unroll
    for (int j = 0; j < 16; ++j) y[j] = 0.0f;

    __syncthreads();

    for (int pass = 0; pass < 2; ++pass) {
        const int n0 = pass * 16;
        // ---------- Phase A: local scans (pairs of n for ILP) ----------
        #pragma unroll
        for (int np = 0; np < 16; np += 2) {
            float wr0 = ldsC[n0 + np],     wi0 = ldsC[32 + n0 + np];
            float wr1 = ldsC[n0 + np + 1], wi1 = ldsC[32 + n0 + np + 1];
            float p0r = 0.f, p0i = 0.f, p1r = 0.f, p1i = 0.f;
            #pragma unroll
            for (int j = 0; j < 16; ++j) {
                float t0r = fmaf(wr0, p0r, fmaf(-wi0, p0i, uv[j]));
                float t0i = fmaf(wr0, p0i, wi0 * p0r);
                float t1r = fmaf(wr1, p1r, fmaf(-wi1, p1i, uv[j]));
                float t1i = fmaf(wr1, p1i, wi1 * p1r);
                p0r = t0r; p0i = t0i; p1r = t1r; p1i = t1i;
            }
            *(float2*)&ldsP[np][tid][0]     = make_float2(p0r, p0i);
            *(float2*)&ldsP[np + 1][tid][0] = make_float2(p1r, p1i);
        }
        __syncthreads();
        // ---------- Phase B: carry scan, wave 0, 16 n x 4 segments ----------
        if (tid < 64) {
            const int n = tid & 15, seg = tid >> 4;
            float Wr = ldsC[128 + n0 + n], Wi = ldsC[160 + n0 + n];  // w^16
            // W16^64 = w^1024 via SIX squarings (w^32,64,128,256,512,1024)
            float ar_ = Wr, ai_ = Wi;
            #pragma unroll
            for (int sq = 0; sq < 6; ++sq) {
                float nr = ar_ * ar_ - ai_ * ai_;
                float ni = 2.0f * ar_ * ai_;
                ar_ = nr; ai_ = ni;
            }
            const float W64r = ar_, W64i = ai_;                      // w^1024
            const int base = seg * 64;
            float sr = 0.f, si = 0.f;
            for (int t = 0; t < 64; ++t) {
                float2 p = *(float2*)&ldsP[n][base + t][0];
                *(float2*)&ldsP[n][base + t][0] = make_float2(sr, si);  // exclusive local
                float nsr = fmaf(Wr, sr, fmaf(-Wi, si, p.x));
                float nsi = fmaf(Wr, si, fmaf(Wi, sr, p.y));
                sr = nsr; si = nsi;
            }
            // cross-segment prefix Q_seg = F_end(seg-1), F_end(s)=W1024*F_end(s-1)+T_s
            float Qr = 0.f, Qi = 0.f;
            #pragma unroll
            for (int sp = 0; sp < 3; ++sp) {
                float tr = __shfl(sr, sp * 16 + n, 64);
                float ti = __shfl(si, sp * 16 + n, 64);
                if (sp < seg) {
                    float nQr = fmaf(W64r, Qr, fmaf(-W64i, Qi, tr));
                    float nQi = fmaf(W64r, Qi, fmaf(W64i, Qr, ti));
                    Qr = nQr; Qi = nQi;
                }
            }
            if (seg > 0) {
                float gr = Qr, gi = Qi;  // S_full(t) = S_local(t) + w^(16(t-base)) * Q
                for (int t = 0; t < 64; ++t) {
                    float2 v = *(float2*)&ldsP[n][base + t][0];
                    v.x += gr; v.y += gi;
                    *(float2*)&ldsP[n][base + t][0] = v;
                    float ngr = Wr * gr - Wi * gi;
                    float ngi = Wr * gi + Wi * gr;
                    gr = ngr; gi = ngi;
                }
            }
        }
        __syncthreads();
        // ---------- Phase C: recompute with carries, accumulate y ----------
        #pragma unroll
        for (int np = 0; np < 16; np += 2) {
            float wr0 = ldsC[n0 + np],     wi0 = ldsC[32 + n0 + np];
            float wr1 = ldsC[n0 + np + 1], wi1 = ldsC[32 + n0 + np + 1];
            float c0r = ldsC[64 + n0 + np],     c0i = ldsC[96 + n0 + np];
            float c1r = ldsC[64 + n0 + np + 1], c1i = ldsC[96 + n0 + np + 1];
            float2 s0 = *(float2*)&ldsP[np][tid][0];
            float2 s1 = *(float2*)&ldsP[np + 1][tid][0];
            float s0r = s0.x, s0i = s0.y, s1r = s1.x, s1i = s1.y;
            #pragma unroll
            for (int j = 0; j < 16; ++j) {
                float t0r = fmaf(wr0, s0r, fmaf(-wi0, s0i, uv[j]));
                float t0i = fmaf(wr0, s0i, wi0 * s0r);
                float t1r = fmaf(wr1, s1r, fmaf(-wi1, s1i, uv[j]));
                float t1i = fmaf(wr1, s1i, wi1 * s1r);
                s0r = t0r; s0i = t0i; s1r = t1r; s1i = t1i;
                y[j] = fmaf(c0r, s0r, fmaf(-c0i, s0i, y[j]));
                y[j] = fmaf(c1r, s1r, fmaf(-c1i, s1i, y[j]));
            }
        }
        if (pass == 0) __syncthreads();
    }

    // ---------- Epilogue: + u*D, exact GELU, bf16 store ----------
    const float dcoef = Dvec[h];
    union { unsigned short us[16]; uint4 q[2]; } pk;
    #pragma unroll
    for (int j = 0; j < 16; ++j) {
        float x = fmaf(uv[j], dcoef, y[j]);
        float g = 0.5f * x * (1.0f + erff(x * 0.70710678118654752f));
        pk.us[j] = f2bf(g);
    }
    uint4* dst = (uint4*)(ybf + (size_t)bh * NL + tid * 16);
    dst[0] = pk.q[0];
    dst[1] = pk.q[1];
}

// z[b,o,l] = sum_h W[o,h]*y[b,h,l] + b_out[o]; out[b,h,l] = z_a * sigmoid(z_b)
// Block tile: 64 h (paired rows o and o+256) x 128 l, K=256 in chunks of 16.
// 256 threads, 8x8 register micro-tile each.
__global__ __launch_bounds__(256) void gemm_glu_kernel(
        const unsigned short* __restrict__ ybf,
        const float* __restrict__ W,
        const float* __restrict__ bo,
        float* __restrict__ out) {
    const int l0  = blockIdx.x * 128;
    const int ho0 = blockIdx.y * 64;
    const int b   = blockIdx.z;
    const int tid = threadIdx.x;
    const int tx = tid & 15, ty = tid >> 4;

    __shared__ float ldsW[16][128];  // [k][o_r]: o_r 0..63 = W[ho0+..], 64..127 = W[256+ho0+..]
    __shared__ float ldsY[16][128];  // [k][l]

    float acc[8][8];
    #pragma unroll
    for (int r = 0; r < 8; ++r)
        #pragma unroll
        for (int c = 0; c < 8; ++c) acc[r][c] = 0.0f;

    const int yrow = tid >> 4;            // 0..15
    const int ycol = (tid & 15) * 8;      // 0..120
    const int o_r  = tid & 127;
    const int half = tid >> 7;            // 0,1
    const int wrow = (o_r < 64) ? (ho0 + o_r) : (NH + ho0 + (o_r - 64));
    const unsigned short* ybase = ybf + (size_t)b * NH * NL + l0;

    for (int kc = 0; kc < 16; ++kc) {
        const int k0 = kc * 16;
        __syncthreads();
        // stage y tile (bf16 -> f32)
        uint4 v = *(const uint4*)(ybase + (size_t)(k0 + yrow) * NL + ycol);
        // stage W tile (transposed)
        const float* wsrc = W + wrow * NH + k0 + half * 8;
        float4 w0 = *(const float4*)wsrc;
        float4 w1 = *(const float4*)(wsrc + 4);
        float4 yv0, yv1;
        yv0.x = bf2f((unsigned short)(v.x & 0xFFFF)); yv0.y = bf2f((unsigned short)(v.x >> 16));
        yv0.z = bf2f((unsigned short)(v.y & 0xFFFF)); yv0.w = bf2f((unsigned short)(v.y >> 16));
        yv1.x = bf2f((unsigned short)(v.z & 0xFFFF)); yv1.y = bf2f((unsigned short)(v.z >> 16));
        yv1.z = bf2f((unsigned short)(v.w & 0xFFFF)); yv1.w = bf2f((unsigned short)(v.w >> 16));
        *(float4*)&ldsY[yrow][ycol]     = yv0;
        *(float4*)&ldsY[yrow][ycol + 4] = yv1;
        const int kb = half * 8;
        ldsW[kb + 0][o_r] = w0.x; ldsW[kb + 1][o_r] = w0.y;
        ldsW[kb + 2][o_r] = w0.z; ldsW[kb + 3][o_r] = w0.w;
        ldsW[kb + 4][o_r] = w1.x; ldsW[kb + 5][o_r] = w1.y;
        ldsW[kb + 6][o_r] = w1.z; ldsW[kb + 7][o_r] = w1.w;
        __syncthreads();
        #pragma unroll
        for (int kk = 0; kk < 16; ++kk) {
            float4 a0 = *(const float4*)&ldsW[kk][ty * 4];
            float4 a1 = *(const float4*)&ldsW[kk][64 + ty * 4];
            float4 b0 = *(const float4*)&ldsY[kk][tx * 4];
            float4 b1 = *(const float4*)&ldsY[kk][64 + tx * 4];
            float av[8] = {a0.x, a0.y, a0.z, a0.w, a1.x, a1.y, a1.z, a1.w};
            float bv[8] = {b0.x, b0.y, b0.z, b0.w, b1.x, b1.y, b1.z, b1.w};
            #pragma unroll
            for (int r = 0; r < 8; ++r)
                #pragma unroll
                for (int c = 0; c < 8; ++c)
                    acc[r][c] = fmaf(av[r], bv[c], acc[r][c]);
        }
    }

    // epilogue: GLU
    #pragma unroll
    for (int r = 0; r < 4; ++r) {
        const int hh = ho0 + ty * 4 + r;
        const float ba = bo[hh], bb = bo[NH + hh];
        float4 o0, o1;
        {
            float za, zb;
            za = acc[r][0] + ba; zb = acc[r + 4][0] + bb; o0.x = za / (1.0f + expf(-zb));
            za = acc[r][1] + ba; zb = acc[r + 4][1] + bb; o0.y = za / (1.0f + expf(-zb));
            za = acc[r][2] + ba; zb = acc[r + 4][2] + bb; o0.z = za / (1.0f + expf(-zb));
            za = acc[r][3] + ba; zb = acc[r + 4][3] + bb; o0.w = za / (1.0f + expf(-zb));
            za = acc[r][4] + ba; zb = acc[r + 4][4] + bb; o1.x = za / (1.0f + expf(-zb));
            za = acc[r][5] + ba; zb = acc[r + 4][5] + bb; o1.y = za / (1.0f + expf(-zb));
            za = acc[r][6] + ba; zb = acc[r + 4][6] + bb; o1.z = za / (1.0f + expf(-zb));
            za = acc[r][7] + ba; zb = acc[r + 4][7] + bb; o1.w = za / (1.0f + expf(-zb));
        }
        float* orow = out + (size_t)(b * NH + hh) * NL + l0;
        *(float4*)(orow + tx * 4)      = o0;
        *(float4*)(orow + 64 + tx * 4) = o1;
    }
}

extern "C" void kernel_launch(void* const* d_in, const int* in_sizes, int n_in,
                              void* d_out, int out_size, void* d_ws, size_t ws_size,
                              hipStream_t stream) {
    (void)in_sizes; (void)n_in; (void)out_size; (void)ws_size;
    const float* u      = (const float*)d_in[0];
    const float* log_dt = (const float*)d_in[1];
    const float* Cr     = (const float*)d_in[2];
    const float* Ci     = (const float*)d_in[3];
    const float* lar    = (const float*)d_in[4];
    const float* aim    = (const float*)d_in[5];
    const float* Dvec   = (const float*)d_in[6];
    const float* W      = (const float*)d_in[7];
    const float* bo     = (const float*)d_in[8];
    float* out = (float*)d_out;

    float* consts = (float*)d_ws;                                   // 192*256*4 = 196608 B
    unsigned short* ybf = (unsigned short*)((char*)d_ws + 192 * NH * 4);  // 33.5 MB

    precompute_kernel<<<dim3((NH * NN + 255) / 256), dim3(256), 0, stream>>>(
        log_dt, Cr, Ci, lar, aim, consts);
    scan_kernel<<<dim3(NB * NH), dim3(256), 0, stream>>>(u, consts, Dvec, ybf);
    gemm_glu_kernel<<<dim3(NL / 128, NH / 64, NB), dim3(256), 0, stream>>>(ybf, W, bo, out);
}

// Round 4
// 206.214 us; speedup vs baseline: 1.6446x; 1.6446x over previous
//
#include <hip/hip_runtime.h>

#define NB 16
#define NH 256
#define NL 4096
#define NN 32

typedef short s8v __attribute__((ext_vector_type(8)));
typedef float f4v __attribute__((ext_vector_type(4)));
typedef unsigned short u8h __attribute__((ext_vector_type(8)));

__device__ __forceinline__ unsigned short f2bf(float x) {
    unsigned int u = __float_as_uint(x);
    unsigned int r = u + 0x7FFFu + ((u >> 16) & 1u);
    return (unsigned short)(r >> 16);
}

// consts layout per h (192 floats): [0..31]=wr [32..63]=wi [64..95]=c2r [96..127]=c2i
// [128..159]=W16r [160..191]=W16i
__global__ void precompute_kernel(const float* __restrict__ log_dt,
                                  const float* __restrict__ Cr,
                                  const float* __restrict__ Ci,
                                  const float* __restrict__ lar,
                                  const float* __restrict__ aim,
                                  float* __restrict__ consts) {
    int idx = blockIdx.x * blockDim.x + threadIdx.x;  // h*32 + n
    if (idx >= NH * NN) return;
    int h = idx >> 5, n = idx & 31;
    float dt = expf(log_dt[h]);
    float ar = -expf(lar[idx]);
    float ai = aim[idx];
    float dar = ar * dt, dai = ai * dt;
    float er = expf(dar);
    float wr = er * cosf(dai), wi = er * sinf(dai);
    float Er = wr - 1.0f, Ei = wi;
    float den = ar * ar + ai * ai;
    float fr = (Er * ar + Ei * ai) / den;
    float fi = (Ei * ar - Er * ai) / den;
    float cr = Cr[idx], ci = Ci[idx];
    float c2r = 2.0f * (cr * fr - ci * fi);
    float c2i = 2.0f * (cr * fi + ci * fr);
    float e16 = expf(16.0f * dar);
    float W16r = e16 * cosf(16.0f * dai);
    float W16i = e16 * sinf(16.0f * dai);
    float* ch = consts + h * 192;
    ch[n]       = wr;  ch[32 + n]  = wi;
    ch[64 + n]  = c2r; ch[96 + n]  = c2i;
    ch[128 + n] = W16r; ch[160 + n] = W16i;
}

__global__ void convert_w_kernel(const float* __restrict__ W,
                                 unsigned short* __restrict__ Wbf) {
    int i = blockIdx.x * blockDim.x + threadIdx.x;  // one float4 per thread
    float4 v = ((const float4*)W)[i];
    ushort4 o;
    o.x = f2bf(v.x); o.y = f2bf(v.y); o.z = f2bf(v.z); o.w = f2bf(v.w);
    ((ushort4*)Wbf)[i] = o;
}

// ---------------- scan (unchanged from passing round) ----------------
__global__ __launch_bounds__(256) void scan_kernel(const float* __restrict__ u,
                                                   const float* __restrict__ consts,
                                                   const float* __restrict__ Dvec,
                                                   unsigned short* __restrict__ ybf) {
    const int bh = blockIdx.x;
    const int h = bh & (NH - 1);
    const int tid = threadIdx.x;

    __shared__ float ldsC[192];
    __shared__ float ldsP[16][257][2];

    if (tid < 192) ldsC[tid] = consts[h * 192 + tid];

    const float* urow = u + (size_t)bh * NL;
    float uv[16];
    {
        const float4* up = (const float4*)(urow + tid * 16);
        float4 a = up[0], b4 = up[1], c4 = up[2], d4 = up[3];
        uv[0]=a.x; uv[1]=a.y; uv[2]=a.z; uv[3]=a.w;
        uv[4]=b4.x; uv[5]=b4.y; uv[6]=b4.z; uv[7]=b4.w;
        uv[8]=c4.x; uv[9]=c4.y; uv[10]=c4.z; uv[11]=c4.w;
        uv[12]=d4.x; uv[13]=d4.y; uv[14]=d4.z; uv[15]=d4.w;
    }
    float y[16];
    #pragma unroll
    for (int j = 0; j < 16; ++j) y[j] = 0.0f;

    __syncthreads();

    for (int pass = 0; pass < 2; ++pass) {
        const int n0 = pass * 16;
        #pragma unroll
        for (int np = 0; np < 16; np += 2) {
            float wr0 = ldsC[n0 + np],     wi0 = ldsC[32 + n0 + np];
            float wr1 = ldsC[n0 + np + 1], wi1 = ldsC[32 + n0 + np + 1];
            float p0r = 0.f, p0i = 0.f, p1r = 0.f, p1i = 0.f;
            #pragma unroll
            for (int j = 0; j < 16; ++j) {
                float t0r = fmaf(wr0, p0r, fmaf(-wi0, p0i, uv[j]));
                float t0i = fmaf(wr0, p0i, wi0 * p0r);
                float t1r = fmaf(wr1, p1r, fmaf(-wi1, p1i, uv[j]));
                float t1i = fmaf(wr1, p1i, wi1 * p1r);
                p0r = t0r; p0i = t0i; p1r = t1r; p1i = t1i;
            }
            *(float2*)&ldsP[np][tid][0]     = make_float2(p0r, p0i);
            *(float2*)&ldsP[np + 1][tid][0] = make_float2(p1r, p1i);
        }
        __syncthreads();
        if (tid < 64) {
            const int n = tid & 15, seg = tid >> 4;
            float Wr = ldsC[128 + n0 + n], Wi = ldsC[160 + n0 + n];
            float ar_ = Wr, ai_ = Wi;
            #pragma unroll
            for (int sq = 0; sq < 6; ++sq) {
                float nr = ar_ * ar_ - ai_ * ai_;
                float ni = 2.0f * ar_ * ai_;
                ar_ = nr; ai_ = ni;
            }
            const float W64r = ar_, W64i = ai_;  // w^1024
            const int base = seg * 64;
            float sr = 0.f, si = 0.f;
            for (int t = 0; t < 64; ++t) {
                float2 p = *(float2*)&ldsP[n][base + t][0];
                *(float2*)&ldsP[n][base + t][0] = make_float2(sr, si);
                float nsr = fmaf(Wr, sr, fmaf(-Wi, si, p.x));
                float nsi = fmaf(Wr, si, fmaf(Wi, sr, p.y));
                sr = nsr; si = nsi;
            }
            float Qr = 0.f, Qi = 0.f;
            #pragma unroll
            for (int sp = 0; sp < 3; ++sp) {
                float tr = __shfl(sr, sp * 16 + n, 64);
                float ti = __shfl(si, sp * 16 + n, 64);
                if (sp < seg) {
                    float nQr = fmaf(W64r, Qr, fmaf(-W64i, Qi, tr));
                    float nQi = fmaf(W64r, Qi, fmaf(W64i, Qr, ti));
                    Qr = nQr; Qi = nQi;
                }
            }
            if (seg > 0) {
                float gr = Qr, gi = Qi;
                for (int t = 0; t < 64; ++t) {
                    float2 v = *(float2*)&ldsP[n][base + t][0];
                    v.x += gr; v.y += gi;
                    *(float2*)&ldsP[n][base + t][0] = v;
                    float ngr = Wr * gr - Wi * gi;
                    float ngi = Wr * gi + Wi * gr;
                    gr = ngr; gi = ngi;
                }
            }
        }
        __syncthreads();
        #pragma unroll
        for (int np = 0; np < 16; np += 2) {
            float wr0 = ldsC[n0 + np],     wi0 = ldsC[32 + n0 + np];
            float wr1 = ldsC[n0 + np + 1], wi1 = ldsC[32 + n0 + np + 1];
            float c0r = ldsC[64 + n0 + np],     c0i = ldsC[96 + n0 + np];
            float c1r = ldsC[64 + n0 + np + 1], c1i = ldsC[96 + n0 + np + 1];
            float2 s0 = *(float2*)&ldsP[np][tid][0];
            float2 s1 = *(float2*)&ldsP[np + 1][tid][0];
            float s0r = s0.x, s0i = s0.y, s1r = s1.x, s1i = s1.y;
            #pragma unroll
            for (int j = 0; j < 16; ++j) {
                float t0r = fmaf(wr0, s0r, fmaf(-wi0, s0i, uv[j]));
                float t0i = fmaf(wr0, s0i, wi0 * s0r);
                float t1r = fmaf(wr1, s1r, fmaf(-wi1, s1i, uv[j]));
                float t1i = fmaf(wr1, s1i, wi1 * s1r);
                s0r = t0r; s0i = t0i; s1r = t1r; s1i = t1i;
                y[j] = fmaf(c0r, s0r, fmaf(-c0i, s0i, y[j]));
                y[j] = fmaf(c1r, s1r, fmaf(-c1i, s1i, y[j]));
            }
        }
        if (pass == 0) __syncthreads();
    }

    const float dcoef = Dvec[h];
    union { unsigned short us[16]; uint4 q[2]; } pk;
    #pragma unroll
    for (int j = 0; j < 16; ++j) {
        float x = fmaf(uv[j], dcoef, y[j]);
        float g = 0.5f * x * (1.0f + erff(x * 0.70710678118654752f));
        pk.us[j] = f2bf(g);
    }
    uint4* dst = (uint4*)(ybf + (size_t)bh * NL + tid * 16);
    dst[0] = pk.q[0];
    dst[1] = pk.q[1];
}

// ---------------- MFMA GEMM + GLU (transpose-on-write LDS staging) ----------------
// z[o,l] = sum_k Wbf[o,k]*y[b,k,l]; out = glu(z_a, z_b), pairs (o, o+256).
// Block: 4 waves 2x2 over M=64 o-pairs x N=128 l. K=256 in 4 chunks of 64.
// LDS ldsY[l 0..127][k 0..63 bf16, stride 72] holds the y-chunk TRANSPOSED so
// B-fragments are plain ds_read_b128 (granule group (row+g+4ksub)%8 = ideal-b128).
// A-fragments (W bf16, 256KB, L2-resident) load straight from global.
__global__ __launch_bounds__(256) void gemm_glu_mfma(
        const unsigned short* __restrict__ ybf,
        const unsigned short* __restrict__ Wbf,
        const float* __restrict__ bo,
        float* __restrict__ out) {
    const int l0  = blockIdx.x * 128;
    const int ho0 = blockIdx.y * 64;
    const int b   = blockIdx.z;
    const int tid = threadIdx.x;
    const int lane = tid & 63;
    const int wid  = tid >> 6;
    const int wm = wid >> 1, wn = wid & 1;
    const int g = lane >> 4, c = lane & 15;

    __shared__ __align__(16) unsigned int ldsY[128 * 36];  // [l][72 bf16] = 18432 B

    f4v acc[4][4];
    #pragma unroll
    for (int m = 0; m < 4; ++m)
        #pragma unroll
        for (int n = 0; n < 4; ++n)
            acc[m][n] = (f4v){0.f, 0.f, 0.f, 0.f};

    // staging map: thread -> k-row pair kp (rows 2kp,2kp+1), l-chunks lc0, lc0+8
    const int kp  = tid & 31;
    const int lc0 = tid >> 5;  // 0..7
    const unsigned short* ysrc = ybf + ((size_t)b * NH + 2 * kp) * NL + l0;

    // W row bases for the 4 m-frags: m=0,1 -> a-rows; m=2,3 -> b-rows (+256)
    int wrow[4];
    wrow[0] = ho0 + wm * 32 + c;
    wrow[1] = wrow[0] + 16;
    wrow[2] = wrow[0] + 256;
    wrow[3] = wrow[1] + 256;

    for (int ks = 0; ks < 4; ++ks) {
        // ---- issue all global loads early (hide under barrier + pack) ----
        const unsigned short* p0 = ysrc + (size_t)ks * 64 * NL;
        uint4 ya0 = *(const uint4*)(p0 + lc0 * 8);
        uint4 yb0 = *(const uint4*)(p0 + NL + lc0 * 8);
        uint4 ya1 = *(const uint4*)(p0 + (lc0 + 8) * 8);
        uint4 yb1 = *(const uint4*)(p0 + NL + (lc0 + 8) * 8);

        s8v afr[2][4];
        #pragma unroll
        for (int m = 0; m < 4; ++m) {
            const unsigned short* wsrc = Wbf + wrow[m] * NH + ks * 64 + g * 8;
            afr[0][m] = *(const s8v*)(wsrc);
            afr[1][m] = *(const s8v*)(wsrc + 32);
        }

        __syncthreads();  // previous chunk's reads done
        // ---- pack-transpose: ldsY[l][kp] = (y[2kp][l], y[2kp+1][l]) ----
        {
            u8h ah = *(const u8h*)&ya0, bh = *(const u8h*)&yb0;
            #pragma unroll
            for (int j = 0; j < 8; ++j)
                ldsY[(lc0 * 8 + j) * 36 + kp] =
                    (unsigned int)ah[j] | ((unsigned int)bh[j] << 16);
            u8h ah1 = *(const u8h*)&ya1, bh1 = *(const u8h*)&yb1;
            #pragma unroll
            for (int j = 0; j < 8; ++j)
                ldsY[((lc0 + 8) * 8 + j) * 36 + kp] =
                    (unsigned int)ah1[j] | ((unsigned int)bh1[j] << 16);
        }
        __syncthreads();

        // ---- B-fragments via ds_read_b128, MFMA ----
        #pragma unroll
        for (int ksub = 0; ksub < 2; ++ksub) {
            s8v bfr[4];
            #pragma unroll
            for (int n = 0; n < 4; ++n) {
                const int row = wn * 64 + n * 16 + c;
                bfr[n] = *(const s8v*)&ldsY[row * 36 + ksub * 16 + g * 4];
            }
            #pragma unroll
            for (int m = 0; m < 4; ++m)
                #pragma unroll
                for (int n = 0; n < 4; ++n)
                    acc[m][n] = __builtin_amdgcn_mfma_f32_16x16x32_bf16(
                        afr[ksub][m], bfr[n], acc[m][n], 0, 0, 0);
        }
    }

    // Epilogue: GLU over in-lane pairs acc[m] (a-rows) and acc[m+2] (b-rows)
    #pragma unroll
    for (int m = 0; m < 2; ++m) {
        const int o0 = ho0 + wm * 32 + m * 16 + g * 4;  // rows o0..o0+3 (reg j)
        float4 ba = *(const float4*)(bo + o0);
        float4 bb = *(const float4*)(bo + NH + o0);
        const float baj[4] = {ba.x, ba.y, ba.z, ba.w};
        const float bbj[4] = {bb.x, bb.y, bb.z, bb.w};
        #pragma unroll
        for (int j = 0; j < 4; ++j) {
            float* orow = out + ((size_t)(b * NH + o0 + j)) * NL + l0 + wn * 64 + c;
            #pragma unroll
            for (int n = 0; n < 4; ++n) {
                float za = acc[m][n][j] + baj[j];
                float zb = acc[m + 2][n][j] + bbj[j];
                orow[n * 16] = za / (1.0f + expf(-zb));
            }
        }
    }
}

extern "C" void kernel_launch(void* const* d_in, const int* in_sizes, int n_in,
                              void* d_out, int out_size, void* d_ws, size_t ws_size,
                              hipStream_t stream) {
    (void)in_sizes; (void)n_in; (void)out_size; (void)ws_size;
    const float* u      = (const float*)d_in[0];
    const float* log_dt = (const float*)d_in[1];
    const float* Cr     = (const float*)d_in[2];
    const float* Ci     = (const float*)d_in[3];
    const float* lar    = (const float*)d_in[4];
    const float* aim    = (const float*)d_in[5];
    const float* Dvec   = (const float*)d_in[6];
    const float* W      = (const float*)d_in[7];
    const float* bo     = (const float*)d_in[8];
    float* out = (float*)d_out;

    float* consts = (float*)d_ws;                                        // 192 KB
    unsigned short* Wbf = (unsigned short*)((char*)d_ws + 196608);       // 256 KB
    unsigned short* ybf = (unsigned short*)((char*)d_ws + 196608 + 262144);  // 33.5 MB

    precompute_kernel<<<dim3((NH * NN + 255) / 256), dim3(256), 0, stream>>>(
        log_dt, Cr, Ci, lar, aim, consts);
    convert_w_kernel<<<dim3(2 * NH * NH / 4 / 256), dim3(256), 0, stream>>>(W, Wbf);
    scan_kernel<<<dim3(NB * NH), dim3(256), 0, stream>>>(u, consts, Dvec, ybf);
    gemm_glu_mfma<<<dim3(NL / 128, NH / 64, NB), dim3(256), 0, stream>>>(ybf, Wbf, bo, out);
}

// Round 5
// 176.005 us; speedup vs baseline: 1.9269x; 1.1716x over previous
//
#include <hip/hip_runtime.h>

#define NB 16
#define NH 256
#define NL 4096
#define NN 32

typedef short s8v __attribute__((ext_vector_type(8)));
typedef float f4v __attribute__((ext_vector_type(4)));

__device__ __forceinline__ unsigned short f2bf(float x) {
    unsigned int u = __float_as_uint(x);
    unsigned int r = u + 0x7FFFu + ((u >> 16) & 1u);
    return (unsigned short)(r >> 16);
}
__device__ __forceinline__ float bf2f(unsigned short b) {
    return __uint_as_float(((unsigned int)b) << 16);
}

// ---------- precompute A: per (h,n): w32 consts, wc stash, Mp rows, E rows ----------
// Mp[h][64x32] bf16: rows 2n=Re(w^{31-t}), 2n+1=Im(w^{31-t})
// E [h][32x64] bf16: E[j][2n]=Re(c2*w^{j+1}), E[j][2n+1]=-Im(c2*w^{j+1})
__global__ void precompute_kernel(const float* __restrict__ log_dt,
                                  const float* __restrict__ Cr,
                                  const float* __restrict__ Ci,
                                  const float* __restrict__ lar,
                                  const float* __restrict__ aim,
                                  float* __restrict__ w32c,
                                  float* __restrict__ wc,
                                  unsigned short* __restrict__ Mp,
                                  unsigned short* __restrict__ Em) {
    int idx = blockIdx.x * blockDim.x + threadIdx.x;  // h*32 + n
    if (idx >= NH * NN) return;
    int h = idx >> 5, n = idx & 31;
    float dt = expf(log_dt[h]);
    float ar = -expf(lar[idx]);
    float ai = aim[idx];
    float dar = ar * dt, dai = ai * dt;
    float er = expf(dar);
    float wr = er * cosf(dai), wi = er * sinf(dai);
    float Er = wr - 1.0f, Ei = wi;
    float den = ar * ar + ai * ai;
    float fr = (Er * ar + Ei * ai) / den;
    float fi = (Ei * ar - Er * ai) / den;
    float cr = Cr[idx], ci = Ci[idx];
    float c2r = 2.0f * (cr * fr - ci * fi);
    float c2i = 2.0f * (cr * fi + ci * fr);
    // w^32 direct
    float e32 = expf(32.0f * dar);
    w32c[h * 64 + 2 * n]     = e32 * cosf(32.0f * dai);
    w32c[h * 64 + 2 * n + 1] = e32 * sinf(32.0f * dai);
    float* wch = wc + h * 128 + n * 4;
    wch[0] = wr; wch[1] = wi; wch[2] = c2r; wch[3] = c2i;
    // Mp rows: w^{31-t}
    unsigned short* mph = Mp + h * 2048;
    float pr = 1.0f, pi = 0.0f;
    for (int e = 0; e < 32; ++e) {
        int t = 31 - e;
        mph[(2 * n) * 32 + t]     = f2bf(pr);
        mph[(2 * n + 1) * 32 + t] = f2bf(pi);
        float npr = pr * wr - pi * wi;
        pi = fmaf(pr, wi, pi * wr);
        pr = npr;
    }
    // E rows: c2*w^{j+1}
    unsigned short* emh = Em + h * 2048;
    float gr = c2r * wr - c2i * wi;
    float gi = fmaf(c2r, wi, c2i * wr);
    for (int j = 0; j < 32; ++j) {
        emh[j * 64 + 2 * n]     = f2bf(gr);
        emh[j * 64 + 2 * n + 1] = f2bf(-gi);
        float ngr = gr * wr - gi * wi;
        gi = fmaf(gr, wi, gi * wr);
        gr = ngr;
    }
}

// ---------- precompute B: Toeplitz T per h: T[j][t] = sum_n Re(c2*w^{j-t}), diag += D ----------
__global__ void tmat_kernel(const float* __restrict__ wc,
                            const float* __restrict__ Dvec,
                            unsigned short* __restrict__ Tm) {
    const int h = blockIdx.x;
    const int t = threadIdx.x;
    __shared__ float Td[32];
    if (t < 32) {
        float acc = 0.0f;
        const float* wch = wc + h * 128;
        for (int n = 0; n < 32; ++n) {
            float wr = wch[n * 4], wi = wch[n * 4 + 1];
            float gr = wch[n * 4 + 2], gi = wch[n * 4 + 3];
            for (int e = 0; e < t; ++e) {
                float ngr = gr * wr - gi * wi;
                gi = fmaf(gr, wi, gi * wr);
                gr = ngr;
            }
            acc += gr;
        }
        Td[t] = acc;
    }
    __syncthreads();
    const float dh = Dvec[h];
    unsigned short* tmh = Tm + h * 1024;
    for (int i = 0; i < 16; ++i) {
        int idx = t * 16 + i;
        int j = idx >> 5, tt = idx & 31;
        float v = (j >= tt) ? Td[j - tt] : 0.0f;
        if (j == tt) v += dh;
        tmh[idx] = f2bf(v);
    }
}

__global__ void convert_w_kernel(const float* __restrict__ W,
                                 unsigned short* __restrict__ Wbf) {
    int i = blockIdx.x * blockDim.x + threadIdx.x;
    float4 v = ((const float4*)W)[i];
    ushort4 o;
    o.x = f2bf(v.x); o.y = f2bf(v.y); o.z = f2bf(v.z); o.w = f2bf(v.w);
    ((ushort4*)Wbf)[i] = o;
}

// ---------- MFMA chunked scan: one block per (b,h), 4 waves ----------
// y = T(32x32)*U + E(32x64)*S ; P = Mp(64x32)*U ; S: cross-chunk recurrence (wave 0).
// U = u row as [chunk 0..127][t 0..31] bf16 (linear). All MFMA frags use the
// verified 16x16x32 layout: A[m=c][k=g*8+j], B[k=g*8+j][col=c], D[4g+r][c].
__global__ __launch_bounds__(256) void scan_mfma_kernel(
        const float* __restrict__ u,
        const float* __restrict__ w32c,
        const unsigned short* __restrict__ Mp,
        const unsigned short* __restrict__ Tm,
        const unsigned short* __restrict__ Em,
        unsigned short* __restrict__ ybf) {
    const int bh = blockIdx.x;
    const int h = bh & (NH - 1);
    const int tid = threadIdx.x;
    const int lane = tid & 63;
    const int wv = tid >> 6;
    const int g = lane >> 4, c = lane & 15;

    __shared__ __align__(16) char arena[41984];
    unsigned short* u_bf = (unsigned short*)arena;            // [4096] bf16, 8192 B
    unsigned int*   ldsP = (unsigned int*)(arena + 8192);     // [128*34] u32 (bf16 pairs), 17408 B
    unsigned int*   ldsS = (unsigned int*)(arena + 25600);    // [128*32] u32 (Sr,Si bf16), 16384 B

    // ---- stage u -> bf16 LDS (linear l order) ----
    {
        const float4* up = (const float4*)(u + (size_t)bh * NL + tid * 16);
        float4 a = up[0], b4 = up[1], c4 = up[2], d4 = up[3];
        union { unsigned short us[16]; uint4 q[2]; } pk;
        pk.us[0]=f2bf(a.x); pk.us[1]=f2bf(a.y); pk.us[2]=f2bf(a.z); pk.us[3]=f2bf(a.w);
        pk.us[4]=f2bf(b4.x); pk.us[5]=f2bf(b4.y); pk.us[6]=f2bf(b4.z); pk.us[7]=f2bf(b4.w);
        pk.us[8]=f2bf(c4.x); pk.us[9]=f2bf(c4.y); pk.us[10]=f2bf(c4.z); pk.us[11]=f2bf(c4.w);
        pk.us[12]=f2bf(d4.x); pk.us[13]=f2bf(d4.y); pk.us[14]=f2bf(d4.z); pk.us[15]=f2bf(d4.w);
        uint4* dst = (uint4*)(u_bf + tid * 16);
        dst[0] = pk.q[0];
        dst[1] = pk.q[1];
    }
    __syncthreads();

    // ---- B-fragments of U for this wave's two 16-chunk column tiles ----
    s8v bu[2];
    #pragma unroll
    for (int ntl = 0; ntl < 2; ++ntl)
        bu[ntl] = *(const s8v*)(u_bf + ((2 * wv + ntl) * 16 + c) * 32 + g * 8);

    // ---- GEMM1: P(64 x 128) = Mp * U ----
    const unsigned short* mph = Mp + h * 2048;
    f4v p1[4][2];
    #pragma unroll
    for (int mt = 0; mt < 4; ++mt) {
        s8v am = *(const s8v*)(mph + (mt * 16 + c) * 32 + g * 8);
        p1[mt][0] = (f4v){0.f,0.f,0.f,0.f};
        p1[mt][1] = (f4v){0.f,0.f,0.f,0.f};
        p1[mt][0] = __builtin_amdgcn_mfma_f32_16x16x32_bf16(am, bu[0], p1[mt][0], 0,0,0);
        p1[mt][1] = __builtin_amdgcn_mfma_f32_16x16x32_bf16(am, bu[1], p1[mt][1], 0,0,0);
    }
    // write P (bf16 pairs) to ldsP[chunk][m/2], stride 34 u32
    #pragma unroll
    for (int mt = 0; mt < 4; ++mt)
        #pragma unroll
        for (int ntl = 0; ntl < 2; ++ntl) {
            const int chunk = (2 * wv + ntl) * 16 + c;
            f4v v = p1[mt][ntl];
            unsigned int lo = (unsigned int)f2bf(v[0]) | ((unsigned int)f2bf(v[1]) << 16);
            unsigned int hi = (unsigned int)f2bf(v[2]) | ((unsigned int)f2bf(v[3]) << 16);
            *(uint2*)&ldsP[chunk * 34 + mt * 8 + 2 * g] = make_uint2(lo, hi);
        }
    __syncthreads();

    // ---- phase B: S recurrence across 128 chunks (wave 0; lane = n + 32*seg) ----
    if (tid < 64) {
        const int n = lane & 31, seg = lane >> 5;
        const float wr = w32c[h * 64 + 2 * n], wi = w32c[h * 64 + 2 * n + 1];
        float sr = 0.f, si = 0.f;
        const int base = seg * 64;
        for (int t = 0; t < 64; ++t) {
            const int chunk = base + t;
            unsigned int pv = ldsP[chunk * 34 + n];
            ldsS[chunk * 32 + n] =
                (unsigned int)f2bf(sr) | ((unsigned int)f2bf(si) << 16);  // exclusive local
            float Pr = bf2f((unsigned short)(pv & 0xFFFF));
            float Pi = bf2f((unsigned short)(pv >> 16));
            float nsr = fmaf(wr, sr, fmaf(-wi, si, Pr));
            float nsi = fmaf(wr, si, fmaf(wi, sr, Pi));
            sr = nsr; si = nsi;
        }
        float tr = __shfl(sr, n, 64);  // seg0 total for mode n
        float ti = __shfl(si, n, 64);
        if (seg == 1) {
            float gr = tr, gi = ti;  // S_full(64+t) = local(t) + w32^t * T0
            for (int t = 0; t < 64; ++t) {
                const int chunk = 64 + t;
                unsigned int sv = ldsS[chunk * 32 + n];
                float fr2 = bf2f((unsigned short)(sv & 0xFFFF)) + gr;
                float fi2 = bf2f((unsigned short)(sv >> 16)) + gi;
                ldsS[chunk * 32 + n] =
                    (unsigned int)f2bf(fr2) | ((unsigned int)f2bf(fi2) << 16);
                float ngr = wr * gr - wi * gi;
                float ngi = fmaf(wr, gi, wi * gr);
                gr = ngr; gi = ngi;
            }
        }
    }
    __syncthreads();

    // ---- GEMM2: Y(32 x 128) = T*U + E*S ----
    const unsigned short* tmh = Tm + h * 1024;
    const unsigned short* emh = Em + h * 2048;
    const unsigned short* sbase = (const unsigned short*)ldsS;
    f4v a2[2][2];
    #pragma unroll
    for (int mt = 0; mt < 2; ++mt) {
        a2[mt][0] = (f4v){0.f,0.f,0.f,0.f};
        a2[mt][1] = (f4v){0.f,0.f,0.f,0.f};
        s8v at = *(const s8v*)(tmh + (mt * 16 + c) * 32 + g * 8);
        a2[mt][0] = __builtin_amdgcn_mfma_f32_16x16x32_bf16(at, bu[0], a2[mt][0], 0,0,0);
        a2[mt][1] = __builtin_amdgcn_mfma_f32_16x16x32_bf16(at, bu[1], a2[mt][1], 0,0,0);
    }
    #pragma unroll
    for (int ksub = 0; ksub < 2; ++ksub) {
        s8v bs[2];
        #pragma unroll
        for (int ntl = 0; ntl < 2; ++ntl) {
            const int chunk = (2 * wv + ntl) * 16 + c;
            bs[ntl] = *(const s8v*)(sbase + chunk * 64 + ksub * 32 + g * 8);
        }
        #pragma unroll
        for (int mt = 0; mt < 2; ++mt) {
            s8v ae = *(const s8v*)(emh + (mt * 16 + c) * 64 + ksub * 32 + g * 8);
            a2[mt][0] = __builtin_amdgcn_mfma_f32_16x16x32_bf16(ae, bs[0], a2[mt][0], 0,0,0);
            a2[mt][1] = __builtin_amdgcn_mfma_f32_16x16x32_bf16(ae, bs[1], a2[mt][1], 0,0,0);
        }
    }

    // ---- epilogue: GELU in regs, direct bf16 store (8 lanes fill each 64B line) ----
    unsigned short* yrow = ybf + (size_t)bh * NL;
    #pragma unroll
    for (int mt = 0; mt < 2; ++mt)
        #pragma unroll
        for (int ntl = 0; ntl < 2; ++ntl) {
            const int chunk = (2 * wv + ntl) * 16 + c;
            f4v v = a2[mt][ntl];
            unsigned short gs[4];
            #pragma unroll
            for (int r = 0; r < 4; ++r) {
                float x = v[r];
                gs[r] = f2bf(0.5f * x * (1.0f + erff(x * 0.70710678118654752f)));
            }
            unsigned int lo = (unsigned int)gs[0] | ((unsigned int)gs[1] << 16);
            unsigned int hi = (unsigned int)gs[2] | ((unsigned int)gs[3] << 16);
            *(uint2*)(yrow + chunk * 32 + mt * 16 + 4 * g) = make_uint2(lo, hi);
        }
}

// ---------------- MFMA GEMM + GLU (unchanged from passing round) ----------------
__global__ __launch_bounds__(256) void gemm_glu_mfma(
        const unsigned short* __restrict__ ybf,
        const unsigned short* __restrict__ Wbf,
        const float* __restrict__ bo,
        float* __restrict__ out) {
    const int l0  = blockIdx.x * 128;
    const int ho0 = blockIdx.y * 64;
    const int b   = blockIdx.z;
    const int tid = threadIdx.x;
    const int lane = tid & 63;
    const int wid  = tid >> 6;
    const int wm = wid >> 1, wn = wid & 1;
    const int g = lane >> 4, c = lane & 15;

    __shared__ __align__(16) unsigned int ldsY[128 * 36];

    f4v acc[4][4];
    #pragma unroll
    for (int m = 0; m < 4; ++m)
        #pragma unroll
        for (int n = 0; n < 4; ++n)
            acc[m][n] = (f4v){0.f, 0.f, 0.f, 0.f};

    const int kp  = tid & 31;
    const int lc0 = tid >> 5;
    const unsigned short* ysrc = ybf + ((size_t)b * NH + 2 * kp) * NL + l0;

    int wrow[4];
    wrow[0] = ho0 + wm * 32 + c;
    wrow[1] = wrow[0] + 16;
    wrow[2] = wrow[0] + 256;
    wrow[3] = wrow[1] + 256;

    for (int ks = 0; ks < 4; ++ks) {
        const unsigned short* p0 = ysrc + (size_t)ks * 64 * NL;
        uint4 ya0 = *(const uint4*)(p0 + lc0 * 8);
        uint4 yb0 = *(const uint4*)(p0 + NL + lc0 * 8);
        uint4 ya1 = *(const uint4*)(p0 + (lc0 + 8) * 8);
        uint4 yb1 = *(const uint4*)(p0 + NL + (lc0 + 8) * 8);

        s8v afr[2][4];
        #pragma unroll
        for (int m = 0; m < 4; ++m) {
            const unsigned short* wsrc = Wbf + wrow[m] * NH + ks * 64 + g * 8;
            afr[0][m] = *(const s8v*)(wsrc);
            afr[1][m] = *(const s8v*)(wsrc + 32);
        }

        __syncthreads();
        {
            typedef unsigned short u8h __attribute__((ext_vector_type(8)));
            u8h ah = *(const u8h*)&ya0, bh = *(const u8h*)&yb0;
            #pragma unroll
            for (int j = 0; j < 8; ++j)
                ldsY[(lc0 * 8 + j) * 36 + kp] =
                    (unsigned int)ah[j] | ((unsigned int)bh[j] << 16);
            u8h ah1 = *(const u8h*)&ya1, bh1 = *(const u8h*)&yb1;
            #pragma unroll
            for (int j = 0; j < 8; ++j)
                ldsY[((lc0 + 8) * 8 + j) * 36 + kp] =
                    (unsigned int)ah1[j] | ((unsigned int)bh1[j] << 16);
        }
        __syncthreads();

        #pragma unroll
        for (int ksub = 0; ksub < 2; ++ksub) {
            s8v bfr[4];
            #pragma unroll
            for (int n = 0; n < 4; ++n) {
                const int row = wn * 64 + n * 16 + c;
                bfr[n] = *(const s8v*)&ldsY[row * 36 + ksub * 16 + g * 4];
            }
            #pragma unroll
            for (int m = 0; m < 4; ++m)
                #pragma unroll
                for (int n = 0; n < 4; ++n)
                    acc[m][n] = __builtin_amdgcn_mfma_f32_16x16x32_bf16(
                        afr[ksub][m], bfr[n], acc[m][n], 0, 0, 0);
        }
    }

    #pragma unroll
    for (int m = 0; m < 2; ++m) {
        const int o0 = ho0 + wm * 32 + m * 16 + g * 4;
        float4 ba = *(const float4*)(bo + o0);
        float4 bb = *(const float4*)(bo + NH + o0);
        const float baj[4] = {ba.x, ba.y, ba.z, ba.w};
        const float bbj[4] = {bb.x, bb.y, bb.z, bb.w};
        #pragma unroll
        for (int j = 0; j < 4; ++j) {
            float* orow = out + ((size_t)(b * NH + o0 + j)) * NL + l0 + wn * 64 + c;
            #pragma unroll
            for (int n = 0; n < 4; ++n) {
                float za = acc[m][n][j] + baj[j];
                float zb = acc[m + 2][n][j] + bbj[j];
                orow[n * 16] = za / (1.0f + expf(-zb));
            }
        }
    }
}

extern "C" void kernel_launch(void* const* d_in, const int* in_sizes, int n_in,
                              void* d_out, int out_size, void* d_ws, size_t ws_size,
                              hipStream_t stream) {
    (void)in_sizes; (void)n_in; (void)out_size; (void)ws_size;
    const float* u      = (const float*)d_in[0];
    const float* log_dt = (const float*)d_in[1];
    const float* Cr     = (const float*)d_in[2];
    const float* Ci     = (const float*)d_in[3];
    const float* lar    = (const float*)d_in[4];
    const float* aim    = (const float*)d_in[5];
    const float* Dvec   = (const float*)d_in[6];
    const float* W      = (const float*)d_in[7];
    const float* bo     = (const float*)d_in[8];
    float* out = (float*)d_out;

    char* ws = (char*)d_ws;
    float*          w32c = (float*)ws;                          // 64 KB
    float*          wc   = (float*)(ws + 65536);                // 128 KB
    unsigned short* Mp   = (unsigned short*)(ws + 196608);      // 1 MB
    unsigned short* Em   = (unsigned short*)(ws + 1245184);     // 1 MB
    unsigned short* Tm   = (unsigned short*)(ws + 2293760);     // 512 KB
    unsigned short* Wbf  = (unsigned short*)(ws + 2818048);     // 256 KB
    unsigned short* ybf  = (unsigned short*)(ws + 3080192);     // 32 MB

    precompute_kernel<<<dim3((NH * NN + 255) / 256), dim3(256), 0, stream>>>(
        log_dt, Cr, Ci, lar, aim, w32c, wc, Mp, Em);
    tmat_kernel<<<dim3(NH), dim3(64), 0, stream>>>(wc, Dvec, Tm);
    convert_w_kernel<<<dim3(2 * NH * NH / 4 / 256), dim3(256), 0, stream>>>(W, Wbf);
    scan_mfma_kernel<<<dim3(NB * NH), dim3(256), 0, stream>>>(u, w32c, Mp, Tm, Em, ybf);
    gemm_glu_mfma<<<dim3(NL / 128, NH / 64, NB), dim3(256), 0, stream>>>(ybf, Wbf, bo, out);
}

// Round 7
// 115.485 us; speedup vs baseline: 2.9367x; 1.5240x over previous
//
#include <hip/hip_runtime.h>

#define NB 16
#define NH 256
#define NL 4096
#define NN 32

typedef short s8v __attribute__((ext_vector_type(8)));
typedef float f4v __attribute__((ext_vector_type(4)));

__device__ __forceinline__ unsigned short f2bf(float x) {
    unsigned int u = __float_as_uint(x);
    unsigned int r = u + 0x7FFFu + ((u >> 16) & 1u);
    return (unsigned short)(r >> 16);
}
__device__ __forceinline__ float bf2f(unsigned short b) {
    return __uint_as_float(((unsigned int)b) << 16);
}

// ---------- merged precompute: per h: w32 consts, Mp, Em, Tm ----------
// Mp[h][64x32] bf16: rows 2n=Re(w^{31-t}), 2n+1=Im(w^{31-t})
// Em[h][32x64] bf16: Em[j][2n]=Re(c2*w^{j+1}), Em[j][2n+1]=-Im(c2*w^{j+1})
// Tm[h][32x32] bf16: T[j][t]=sum_n Re(c2*w^{j-t}) (j>=t), diag += D
__global__ __launch_bounds__(64) void precompute_kernel(
        const float* __restrict__ log_dt,
        const float* __restrict__ Cr,
        const float* __restrict__ Ci,
        const float* __restrict__ lar,
        const float* __restrict__ aim,
        const float* __restrict__ Dvec,
        float* __restrict__ w32c,
        unsigned short* __restrict__ Mp,
        unsigned short* __restrict__ Em,
        unsigned short* __restrict__ Tm) {
    const int h = blockIdx.x;
    const int tid = threadIdx.x;
    __shared__ float sRe[32][33];           // [e][n], padded
    __shared__ float sTd[32];
    __shared__ unsigned short sMp[64 * 32];
    __shared__ unsigned short sEm[32 * 64];

    if (tid < 32) {
        const int n = tid;
        const int idx = h * 32 + n;
        float dt = expf(log_dt[h]);
        float ar = -expf(lar[idx]);
        float ai = aim[idx];
        float dar = ar * dt, dai = ai * dt;
        float er = expf(dar);
        float wr = er * cosf(dai), wi = er * sinf(dai);
        float Er = wr - 1.0f, Ei = wi;
        float den = ar * ar + ai * ai;
        float fr = (Er * ar + Ei * ai) / den;
        float fi = (Ei * ar - Er * ai) / den;
        float cr = Cr[idx], ci = Ci[idx];
        float c2r = 2.0f * (cr * fr - ci * fi);
        float c2i = 2.0f * (cr * fi + ci * fr);
        float e32 = expf(32.0f * dar);
        w32c[h * 64 + 2 * n]     = e32 * cosf(32.0f * dai);
        w32c[h * 64 + 2 * n + 1] = e32 * sinf(32.0f * dai);
        // Mp rows: w^{31-t}
        float pr = 1.0f, pi = 0.0f;
        for (int e = 0; e < 32; ++e) {
            sMp[(2 * n) * 32 + (31 - e)]     = f2bf(pr);
            sMp[(2 * n + 1) * 32 + (31 - e)] = f2bf(pi);
            float npr = pr * wr - pi * wi;
            pi = fmaf(pr, wi, pi * wr);
            pr = npr;
        }
        // g_e = c2*w^e, e=0..32: sRe rows (e<32) + Em rows (e>=1)
        float gr = c2r, gi = c2i;
        for (int e = 0; e <= 32; ++e) {
            if (e < 32) sRe[e][n] = gr;
            if (e >= 1) {
                sEm[(e - 1) * 64 + 2 * n]     = f2bf(gr);
                sEm[(e - 1) * 64 + 2 * n + 1] = f2bf(-gi);
            }
            float ngr = gr * wr - gi * wi;
            gi = fmaf(gr, wi, gi * wr);
            gr = ngr;
        }
    }
    __syncthreads();
    if (tid < 32) {
        float a = 0.0f;
        #pragma unroll
        for (int n = 0; n < 32; ++n) a += sRe[tid][n];
        sTd[tid] = a;
    }
    __syncthreads();
    const float dh = Dvec[h];
    unsigned short* tmh = Tm + h * 1024;
    for (int i = 0; i < 16; ++i) {
        int idx = tid * 16 + i;
        int j = idx >> 5, tt = idx & 31;
        float v = (j >= tt) ? sTd[j - tt] : 0.0f;
        if (j == tt) v += dh;
        tmh[idx] = f2bf(v);
    }
    // coalesced stores of Mp/Em (256 uint4 each, 4 per thread)
    uint4* mp4 = (uint4*)(Mp + h * 2048);
    uint4* em4 = (uint4*)(Em + h * 2048);
    const uint4* smp4 = (const uint4*)sMp;
    const uint4* sem4 = (const uint4*)sEm;
    #pragma unroll
    for (int k = 0; k < 4; ++k) {
        mp4[k * 64 + tid] = smp4[k * 64 + tid];
        em4[k * 64 + tid] = sem4[k * 64 + tid];
    }
}

__global__ void convert_w_kernel(const float* __restrict__ W,
                                 unsigned short* __restrict__ Wbf) {
    int i = blockIdx.x * blockDim.x + threadIdx.x;
    float4 v = ((const float4*)W)[i];
    ushort4 o;
    o.x = f2bf(v.x); o.y = f2bf(v.y); o.z = f2bf(v.z); o.w = f2bf(v.w);
    ((ushort4*)Wbf)[i] = o;
}

// ---------- MFMA chunked scan: one block per (b,h), 4 waves ----------
// y = T(32x32)*U + E(32x64)*S ; P = Mp(64x32)*U ; S recurrence on wave 0.
// ldsP (stride 36 u32, 16B-aligned rows) holds P then is overwritten in place by S.
__global__ __launch_bounds__(256) void scan_mfma_kernel(
        const float* __restrict__ u,
        const float* __restrict__ w32c,
        const unsigned short* __restrict__ Mp,
        const unsigned short* __restrict__ Tm,
        const unsigned short* __restrict__ Em,
        unsigned short* __restrict__ ybf) {
    const int bh = blockIdx.x;
    const int h = bh & (NH - 1);
    const int tid = threadIdx.x;
    const int lane = tid & 63;
    const int wv = tid >> 6;
    const int g = lane >> 4, c = lane & 15;

    __shared__ __align__(16) char arena[26624];
    unsigned short* u_bf = (unsigned short*)arena;            // [4096] bf16, 8192 B
    unsigned int*   ldsP = (unsigned int*)(arena + 8192);     // [128][36] u32, 18432 B

    // ---- stage u -> bf16 LDS (linear l order) ----
    {
        const float4* up = (const float4*)(u + (size_t)bh * NL + tid * 16);
        float4 a = up[0], b4 = up[1], c4 = up[2], d4 = up[3];
        union { unsigned short us[16]; uint4 q[2]; } pk;
        pk.us[0]=f2bf(a.x); pk.us[1]=f2bf(a.y); pk.us[2]=f2bf(a.z); pk.us[3]=f2bf(a.w);
        pk.us[4]=f2bf(b4.x); pk.us[5]=f2bf(b4.y); pk.us[6]=f2bf(b4.z); pk.us[7]=f2bf(b4.w);
        pk.us[8]=f2bf(c4.x); pk.us[9]=f2bf(c4.y); pk.us[10]=f2bf(c4.z); pk.us[11]=f2bf(c4.w);
        pk.us[12]=f2bf(d4.x); pk.us[13]=f2bf(d4.y); pk.us[14]=f2bf(d4.z); pk.us[15]=f2bf(d4.w);
        uint4* dst = (uint4*)(u_bf + tid * 16);
        dst[0] = pk.q[0];
        dst[1] = pk.q[1];
    }
    __syncthreads();

    // ---- B-fragments of U for this wave's two 16-chunk column tiles ----
    s8v bu[2];
    #pragma unroll
    for (int ntl = 0; ntl < 2; ++ntl)
        bu[ntl] = *(const s8v*)(u_bf + ((2 * wv + ntl) * 16 + c) * 32 + g * 8);

    // ---- GEMM1: P(64 x 128) = Mp * U ----
    const unsigned short* mph = Mp + h * 2048;
    f4v p1[4][2];
    #pragma unroll
    for (int mt = 0; mt < 4; ++mt) {
        s8v am = *(const s8v*)(mph + (mt * 16 + c) * 32 + g * 8);
        p1[mt][0] = (f4v){0.f,0.f,0.f,0.f};
        p1[mt][1] = (f4v){0.f,0.f,0.f,0.f};
        p1[mt][0] = __builtin_amdgcn_mfma_f32_16x16x32_bf16(am, bu[0], p1[mt][0], 0,0,0);
        p1[mt][1] = __builtin_amdgcn_mfma_f32_16x16x32_bf16(am, bu[1], p1[mt][1], 0,0,0);
    }
    #pragma unroll
    for (int mt = 0; mt < 4; ++mt)
        #pragma unroll
        for (int ntl = 0; ntl < 2; ++ntl) {
            const int chunk = (2 * wv + ntl) * 16 + c;
            f4v v = p1[mt][ntl];
            unsigned int lo = (unsigned int)f2bf(v[0]) | ((unsigned int)f2bf(v[1]) << 16);
            unsigned int hi = (unsigned int)f2bf(v[2]) | ((unsigned int)f2bf(v[3]) << 16);
            *(uint2*)&ldsP[chunk * 36 + mt * 8 + 2 * g] = make_uint2(lo, hi);
        }
    __syncthreads();

    // ---- phase B: S recurrence across 128 chunks (wave 0), S overwrites P ----
    if (tid < 64) {
        const int n = lane & 31, seg = lane >> 5;
        const float wr = w32c[h * 64 + 2 * n], wi = w32c[h * 64 + 2 * n + 1];
        float sr = 0.f, si = 0.f;
        const int base = seg * 64;
        for (int t = 0; t < 64; ++t) {
            const int chunk = base + t;
            unsigned int pv = ldsP[chunk * 36 + n];
            ldsP[chunk * 36 + n] =
                (unsigned int)f2bf(sr) | ((unsigned int)f2bf(si) << 16);  // exclusive local
            float Pr = bf2f((unsigned short)(pv & 0xFFFF));
            float Pi = bf2f((unsigned short)(pv >> 16));
            float nsr = fmaf(wr, sr, fmaf(-wi, si, Pr));
            float nsi = fmaf(wr, si, fmaf(wi, sr, Pi));
            sr = nsr; si = nsi;
        }
        float tr = __shfl(sr, n, 64);  // seg0 total for mode n
        float ti = __shfl(si, n, 64);
        if (seg == 1) {
            float gr = tr, gi = ti;  // S_full(64+t) = local(t) + w32^t * T0
            for (int t = 0; t < 64; ++t) {
                const int chunk = 64 + t;
                unsigned int sv = ldsP[chunk * 36 + n];
                float fr2 = bf2f((unsigned short)(sv & 0xFFFF)) + gr;
                float fi2 = bf2f((unsigned short)(sv >> 16)) + gi;
                ldsP[chunk * 36 + n] =
                    (unsigned int)f2bf(fr2) | ((unsigned int)f2bf(fi2) << 16);
                float ngr = wr * gr - wi * gi;
                float ngi = fmaf(wr, gi, wi * gr);
                gr = ngr; gi = ngi;
            }
        }
    }
    __syncthreads();

    // ---- GEMM2: Y(32 x 128) = T*U + E*S ----
    const unsigned short* tmh = Tm + h * 1024;
    const unsigned short* emh = Em + h * 2048;
    const unsigned short* sbase = (const unsigned short*)ldsP;
    f4v a2[2][2];
    #pragma unroll
    for (int mt = 0; mt < 2; ++mt) {
        a2[mt][0] = (f4v){0.f,0.f,0.f,0.f};
        a2[mt][1] = (f4v){0.f,0.f,0.f,0.f};
        s8v at = *(const s8v*)(tmh + (mt * 16 + c) * 32 + g * 8);
        a2[mt][0] = __builtin_amdgcn_mfma_f32_16x16x32_bf16(at, bu[0], a2[mt][0], 0,0,0);
        a2[mt][1] = __builtin_amdgcn_mfma_f32_16x16x32_bf16(at, bu[1], a2[mt][1], 0,0,0);
    }
    #pragma unroll
    for (int ksub = 0; ksub < 2; ++ksub) {
        s8v bs[2];
        #pragma unroll
        for (int ntl = 0; ntl < 2; ++ntl) {
            const int chunk = (2 * wv + ntl) * 16 + c;
            bs[ntl] = *(const s8v*)(sbase + chunk * 72 + ksub * 32 + g * 8);
        }
        #pragma unroll
        for (int mt = 0; mt < 2; ++mt) {
            s8v ae = *(const s8v*)(emh + (mt * 16 + c) * 64 + ksub * 32 + g * 8);
            a2[mt][0] = __builtin_amdgcn_mfma_f32_16x16x32_bf16(ae, bs[0], a2[mt][0], 0,0,0);
            a2[mt][1] = __builtin_amdgcn_mfma_f32_16x16x32_bf16(ae, bs[1], a2[mt][1], 0,0,0);
        }
    }

    // ---- epilogue: EXACT erf-GELU (reverted), direct bf16 store ----
    unsigned short* yrow = ybf + (size_t)bh * NL;
    #pragma unroll
    for (int mt = 0; mt < 2; ++mt)
        #pragma unroll
        for (int ntl = 0; ntl < 2; ++ntl) {
            const int chunk = (2 * wv + ntl) * 16 + c;
            f4v v = a2[mt][ntl];
            unsigned short gs[4];
            #pragma unroll
            for (int r = 0; r < 4; ++r) {
                float x = v[r];
                gs[r] = f2bf(0.5f * x * (1.0f + erff(x * 0.70710678118654752f)));
            }
            unsigned int lo = (unsigned int)gs[0] | ((unsigned int)gs[1] << 16);
            unsigned int hi = (unsigned int)gs[2] | ((unsigned int)gs[3] << 16);
            *(uint2*)(yrow + chunk * 32 + mt * 16 + 4 * g) = make_uint2(lo, hi);
        }
}

// ---------------- MFMA GEMM + GLU ----------------
__global__ __launch_bounds__(256) void gemm_glu_mfma(
        const unsigned short* __restrict__ ybf,
        const unsigned short* __restrict__ Wbf,
        const float* __restrict__ bo,
        float* __restrict__ out) {
    const int l0  = blockIdx.x * 128;
    const int ho0 = blockIdx.y * 64;
    const int b   = blockIdx.z;
    const int tid = threadIdx.x;
    const int lane = tid & 63;
    const int wid  = tid >> 6;
    const int wm = wid >> 1, wn = wid & 1;
    const int g = lane >> 4, c = lane & 15;

    __shared__ __align__(16) unsigned int ldsY[128 * 36];

    f4v acc[4][4];
    #pragma unroll
    for (int m = 0; m < 4; ++m)
        #pragma unroll
        for (int n = 0; n < 4; ++n)
            acc[m][n] = (f4v){0.f, 0.f, 0.f, 0.f};

    const int kp  = tid & 31;
    const int lc0 = tid >> 5;
    const unsigned short* ysrc = ybf + ((size_t)b * NH + 2 * kp) * NL + l0;

    int wrow[4];
    wrow[0] = ho0 + wm * 32 + c;
    wrow[1] = wrow[0] + 16;
    wrow[2] = wrow[0] + 256;
    wrow[3] = wrow[1] + 256;

    for (int ks = 0; ks < 4; ++ks) {
        const unsigned short* p0 = ysrc + (size_t)ks * 64 * NL;
        uint4 ya0 = *(const uint4*)(p0 + lc0 * 8);
        uint4 yb0 = *(const uint4*)(p0 + NL + lc0 * 8);
        uint4 ya1 = *(const uint4*)(p0 + (lc0 + 8) * 8);
        uint4 yb1 = *(const uint4*)(p0 + NL + (lc0 + 8) * 8);

        s8v afr[2][4];
        #pragma unroll
        for (int m = 0; m < 4; ++m) {
            const unsigned short* wsrc = Wbf + wrow[m] * NH + ks * 64 + g * 8;
            afr[0][m] = *(const s8v*)(wsrc);
            afr[1][m] = *(const s8v*)(wsrc + 32);
        }

        __syncthreads();
        {
            typedef unsigned short u8h __attribute__((ext_vector_type(8)));
            u8h ah = *(const u8h*)&ya0, bh = *(const u8h*)&yb0;
            #pragma unroll
            for (int j = 0; j < 8; ++j)
                ldsY[(lc0 * 8 + j) * 36 + kp] =
                    (unsigned int)ah[j] | ((unsigned int)bh[j] << 16);
            u8h ah1 = *(const u8h*)&ya1, bh1 = *(const u8h*)&yb1;
            #pragma unroll
            for (int j = 0; j < 8; ++j)
                ldsY[((lc0 + 8) * 8 + j) * 36 + kp] =
                    (unsigned int)ah1[j] | ((unsigned int)bh1[j] << 16);
        }
        __syncthreads();

        #pragma unroll
        for (int ksub = 0; ksub < 2; ++ksub) {
            s8v bfr[4];
            #pragma unroll
            for (int n = 0; n < 4; ++n) {
                const int row = wn * 64 + n * 16 + c;
                bfr[n] = *(const s8v*)&ldsY[row * 36 + ksub * 16 + g * 4];
            }
            #pragma unroll
            for (int m = 0; m < 4; ++m)
                #pragma unroll
                for (int n = 0; n < 4; ++n)
                    acc[m][n] = __builtin_amdgcn_mfma_f32_16x16x32_bf16(
                        afr[ksub][m], bfr[n], acc[m][n], 0, 0, 0);
        }
    }

    #pragma unroll
    for (int m = 0; m < 2; ++m) {
        const int o0 = ho0 + wm * 32 + m * 16 + g * 4;
        float4 ba = *(const float4*)(bo + o0);
        float4 bb = *(const float4*)(bo + NH + o0);
        const float baj[4] = {ba.x, ba.y, ba.z, ba.w};
        const float bbj[4] = {bb.x, bb.y, bb.z, bb.w};
        #pragma unroll
        for (int j = 0; j < 4; ++j) {
            float* orow = out + ((size_t)(b * NH + o0 + j)) * NL + l0 + wn * 64 + c;
            #pragma unroll
            for (int n = 0; n < 4; ++n) {
                float za = acc[m][n][j] + baj[j];
                float zb = acc[m + 2][n][j] + bbj[j];
                orow[n * 16] = za / (1.0f + expf(-zb));
            }
        }
    }
}

extern "C" void kernel_launch(void* const* d_in, const int* in_sizes, int n_in,
                              void* d_out, int out_size, void* d_ws, size_t ws_size,
                              hipStream_t stream) {
    (void)in_sizes; (void)n_in; (void)out_size; (void)ws_size;
    const float* u      = (const float*)d_in[0];
    const float* log_dt = (const float*)d_in[1];
    const float* Cr     = (const float*)d_in[2];
    const float* Ci     = (const float*)d_in[3];
    const float* lar    = (const float*)d_in[4];
    const float* aim    = (const float*)d_in[5];
    const float* Dvec   = (const float*)d_in[6];
    const float* W      = (const float*)d_in[7];
    const float* bo     = (const float*)d_in[8];
    float* out = (float*)d_out;

    char* ws = (char*)d_ws;
    float*          w32c = (float*)ws;                          // 64 KB
    unsigned short* Mp   = (unsigned short*)(ws + 65536);       // 1 MB
    unsigned short* Em   = (unsigned short*)(ws + 1114112);     // 1 MB
    unsigned short* Tm   = (unsigned short*)(ws + 2162688);     // 512 KB
    unsigned short* Wbf  = (unsigned short*)(ws + 2686976);     // 256 KB
    unsigned short* ybf  = (unsigned short*)(ws + 2949120);     // 32 MB

    precompute_kernel<<<dim3(NH), dim3(64), 0, stream>>>(
        log_dt, Cr, Ci, lar, aim, Dvec, w32c, Mp, Em, Tm);
    convert_w_kernel<<<dim3(2 * NH * NH / 4 / 256), dim3(256), 0, stream>>>(W, Wbf);
    scan_mfma_kernel<<<dim3(NB * NH), dim3(256), 0, stream>>>(u, w32c, Mp, Tm, Em, ybf);
    gemm_glu_mfma<<<dim3(NL / 128, NH / 64, NB), dim3(256), 0, stream>>>(ybf, Wbf, bo, out);
}